// Round 1
// baseline (16082.613 us; speedup 1.0000x reference)
//
#include <hip/hip_runtime.h>
#include <hip/hip_bf16.h>

#define B_   1024
#define L_   50
#define E_   128
#define H_   128
#define G_   384      // 3*H
#define NI_  100000

// ---------------------------------------------------------------- lengths
__global__ void k_len(const int* __restrict__ items, int* __restrict__ len) {
    int b = blockIdx.x * 256 + threadIdx.x;
    if (b >= B_) return;
    int c = 0;
    #pragma unroll
    for (int l = 0; l < L_; ++l) c += (items[b * L_ + l] != 0);
    len[b] = c > 0 ? c : 1;
}

// ------------------------------------------------- gates_x = gather+GEMM
// grid: 51200/32 = 1600 blocks, 384 threads. Block handles 32 (b,l) rows,
// thread g handles one output gate column.
__global__ __launch_bounds__(384) void k_gates(const int* __restrict__ items,
                                               const float* __restrict__ emb,
                                               const float* __restrict__ Wih,
                                               const float* __restrict__ bih,
                                               float* __restrict__ gx) {
    __shared__ float4 xs[32][32];            // [row][kquad], broadcast reads
    const int m0 = blockIdx.x * 32;
    const int tid = threadIdx.x;
    for (int i = tid; i < 32 * 32; i += 384) {
        int r = i >> 5, kq = i & 31;
        int it = items[m0 + r];
        xs[r][kq] = ((const float4*)emb)[(size_t)it * 32 + kq];
    }
    __syncthreads();
    const int g = tid;                       // 0..383
    float acc[32];
    #pragma unroll
    for (int r = 0; r < 32; ++r) acc[r] = 0.0f;
    const float4* W4 = (const float4*)Wih;
    #pragma unroll
    for (int kq = 0; kq < 32; ++kq) {
        float4 w = W4[g * 32 + kq];
        #pragma unroll
        for (int r = 0; r < 32; ++r) {
            float4 x = xs[r][kq];
            acc[r] += x.x * w.x + x.y * w.y + x.z * w.z + x.w * w.w;
        }
    }
    const float bb = bih[g];
    #pragma unroll
    for (int r = 0; r < 32; ++r)
        gx[(size_t)(m0 + r) * G_ + g] = acc[r] + bb;
}

// ------------------------------------------------------- GRU recurrence
// 256 blocks x 384 threads; block owns 4 batch rows for all 50 steps.
// Thread g keeps W_hh[g,:] in 128 VGPRs; h lives in LDS (broadcast reads).
__global__ __launch_bounds__(384, 1) void k_gru(const float* __restrict__ gx,
                                                const float* __restrict__ Whh,
                                                const float* __restrict__ bhh,
                                                const int* __restrict__ len,
                                                float* __restrict__ last) {
    __shared__ float4 hs[4][32];             // h state, [row][kquad]
    __shared__ float  ghs[4][G_];            // gh scratch per step
    __shared__ int    lens[4];
    const int b0 = blockIdx.x * 4;
    const int g  = threadIdx.x;

    float4 w[32];
    const float4* W4 = (const float4*)Whh;
    #pragma unroll
    for (int kq = 0; kq < 32; ++kq) w[kq] = W4[g * 32 + kq];
    const float bg = bhh[g];

    if (g < 4) lens[g] = len[b0 + g];
    for (int i = g; i < 4 * 32; i += 384) hs[i >> 5][i & 31] = make_float4(0.f, 0.f, 0.f, 0.f);
    __syncthreads();

    for (int t = 0; t < L_; ++t) {
        float a0 = bg, a1 = bg, a2 = bg, a3 = bg;
        #pragma unroll
        for (int kq = 0; kq < 32; ++kq) {
            float4 wv = w[kq];
            float4 h0 = hs[0][kq], h1 = hs[1][kq], h2 = hs[2][kq], h3 = hs[3][kq];
            a0 += h0.x * wv.x + h0.y * wv.y + h0.z * wv.z + h0.w * wv.w;
            a1 += h1.x * wv.x + h1.y * wv.y + h1.z * wv.z + h1.w * wv.w;
            a2 += h2.x * wv.x + h2.y * wv.y + h2.z * wv.z + h2.w * wv.w;
            a3 += h3.x * wv.x + h3.y * wv.y + h3.z * wv.z + h3.w * wv.w;
        }
        ghs[0][g] = a0; ghs[1][g] = a1; ghs[2][g] = a2; ghs[3][g] = a3;
        __syncthreads();
        for (int i = g; i < 4 * 128; i += 384) {
            int r = i >> 7, j = i & 127;
            size_t base = ((size_t)(b0 + r) * L_ + t) * G_;
            float xr = gx[base + j], xz = gx[base + 128 + j], xn = gx[base + 256 + j];
            float hr = ghs[r][j],    hz = ghs[r][128 + j],    hn = ghs[r][256 + j];
            float rg = 1.0f / (1.0f + expf(-(xr + hr)));
            float z  = 1.0f / (1.0f + expf(-(xz + hz)));
            float nn = tanhf(xn + rg * hn);
            float hp = ((const float*)hs[r])[j];
            float hv = (1.0f - z) * nn + z * hp;
            ((float*)hs[r])[j] = hv;
            if (t == lens[r] - 1) last[(size_t)(b0 + r) * H_ + j] = hv;
        }
        __syncthreads();
    }
}

// ----------------------------------------------------------- cls = last @ Wproj^T
__global__ __launch_bounds__(128) void k_cls(const float* __restrict__ last,
                                             const float* __restrict__ Wp,
                                             float* __restrict__ cls) {
    __shared__ float4 hl[32];
    const int b = blockIdx.x, e = threadIdx.x;
    if (e < 32) hl[e] = ((const float4*)last)[b * 32 + e];
    __syncthreads();
    float acc = 0.0f;
    const float4* W4 = (const float4*)Wp;
    #pragma unroll
    for (int kq = 0; kq < 32; ++kq) {
        float4 w = W4[e * 32 + kq];
        float4 h = hl[kq];
        acc += h.x * w.x + h.y * w.y + h.z * w.z + h.w * w.w;
    }
    cls[(size_t)b * E_ + e] = acc;
}

// ----------------------------------------------------- scores = cls @ emb^T + bias
// 64x64 tile, 256 threads, 4x4 microtile, K=128 fully staged.
// LDS exactly 64 KB; XOR swizzle (kq ^ (row&7)) kills the 512B-row-stride
// bank conflict (row stride == 0 mod 32 banks otherwise).
__global__ __launch_bounds__(256) void k_scores(const float* __restrict__ cls,
                                                const float* __restrict__ emb,
                                                const float* __restrict__ bias,
                                                float* __restrict__ out) {
    __shared__ float4 As[64][32];
    __shared__ float4 Bs[64][32];
    const int n0 = blockIdx.x * 64, m0 = blockIdx.y * 64;
    const int tid = threadIdx.x;
    const int tx = tid & 15, ty = tid >> 4;

    for (int i = tid; i < 2048; i += 256) {
        int r = i >> 5, kq = i & 31;
        As[r][kq ^ (r & 7)] = ((const float4*)cls)[(size_t)(m0 + r) * 32 + kq];
        int n = n0 + r;
        Bs[r][kq ^ (r & 7)] = (n < NI_) ? ((const float4*)emb)[(size_t)n * 32 + kq]
                                        : make_float4(0.f, 0.f, 0.f, 0.f);
    }
    __syncthreads();

    float acc[4][4] = {};
    #pragma unroll
    for (int kq = 0; kq < 32; ++kq) {
        float4 a[4], b[4];
        #pragma unroll
        for (int i = 0; i < 4; ++i) a[i] = As[ty + i * 16][kq ^ (ty & 7)];
        #pragma unroll
        for (int j = 0; j < 4; ++j) b[j] = Bs[tx + j * 16][kq ^ (tx & 7)];
        #pragma unroll
        for (int i = 0; i < 4; ++i)
            #pragma unroll
            for (int j = 0; j < 4; ++j)
                acc[i][j] += a[i].x * b[j].x + a[i].y * b[j].y +
                             a[i].z * b[j].z + a[i].w * b[j].w;
    }

    #pragma unroll
    for (int i = 0; i < 4; ++i) {
        int m = m0 + ty + i * 16;
        #pragma unroll
        for (int j = 0; j < 4; ++j) {
            int n = n0 + tx + j * 16;
            if (n < NI_) out[(size_t)m * NI_ + n] = acc[i][j] + bias[n];
        }
    }
}

// ---------------------------------------------------------------- launch
extern "C" void kernel_launch(void* const* d_in, const int* in_sizes, int n_in,
                              void* d_out, int out_size, void* d_ws, size_t ws_size,
                              hipStream_t stream) {
    const int*   items = (const int*)  d_in[0];
    const float* emb   = (const float*)d_in[1];
    const float* Wih   = (const float*)d_in[2];
    const float* Whh   = (const float*)d_in[3];
    const float* bih   = (const float*)d_in[4];
    const float* bhh   = (const float*)d_in[5];
    const float* Wp    = (const float*)d_in[6];
    const float* bias  = (const float*)d_in[7];
    float* out = (float*)d_out;

    // workspace layout (all 256B aligned)
    char* ws = (char*)d_ws;
    float* gx   = (float*)(ws);                                   // 78,643,200 B
    int*   len  = (int*)  (ws + 78643200);                        //      4,096 B
    float* last = (float*)(ws + 78643200 + 4096);                 //    524,288 B
    float* cls  = (float*)(ws + 78643200 + 4096 + 524288);        //    524,288 B

    k_len   <<<dim3((B_ + 255) / 256), dim3(256), 0, stream>>>(items, len);
    k_gates <<<dim3((B_ * L_) / 32),   dim3(384), 0, stream>>>(items, emb, Wih, bih, gx);
    k_gru   <<<dim3(B_ / 4),           dim3(384), 0, stream>>>(gx, Whh, bhh, len, last);
    k_cls   <<<dim3(B_),               dim3(128), 0, stream>>>(last, Wp, cls);
    k_scores<<<dim3((NI_ + 63) / 64, B_ / 64), dim3(256), 0, stream>>>(cls, emb, bias, out);
}